// Round 2
// baseline (2700.900 us; speedup 1.0000x reference)
//
#include <hip/hip_runtime.h>
#include <hip/hip_bf16.h>
#include <cstdint>

typedef __hip_bfloat16 bf16;
typedef __attribute__((ext_vector_type(8))) short v8s;
typedef __attribute__((ext_vector_type(4))) float v4f;

// swizzled LDS address for 128B-row tiles: XOR 16B-slot bits with (row&7)  [guide G4]
#define SWZ(base, row, bytecol) ((base) + (row) * 128 + ((bytecol) ^ (((row) & 7) << 4)))

__device__ __forceinline__ void gload16(const void* g, void* l) {
  __builtin_amdgcn_global_load_lds((__attribute__((address_space(1))) void*)g,
                                   (__attribute__((address_space(3))) void*)l, 16, 0, 0);
}

__device__ __forceinline__ v4f mfma16(v8s a, v8s b, v4f c) {
  return __builtin_amdgcn_mfma_f32_16x16x32_bf16(a, b, c, 0, 0, 0);
}

__device__ __forceinline__ float blocksum(float v, float* red, int tid) {
#pragma unroll
  for (int o = 32; o > 0; o >>= 1) v += __shfl_xor(v, o);
  if ((tid & 63) == 0) red[tid >> 6] = v;
  __syncthreads();
  float r = red[0] + red[1] + red[2] + red[3];
  __syncthreads();
  return r;
}

// ---------------- embed: xs@W + b -> LN -> relu -> posenc ----------------
__global__ __launch_bounds__(256) void embed_kernel(
    const float* __restrict__ xs, const float* __restrict__ w, const float* __restrict__ bb,
    const float* __restrict__ g, const float* __restrict__ beta, float* __restrict__ xout) {
  const int tok = blockIdx.x;
  const int tid = threadIdx.x;
  __shared__ float xrow[80];
  __shared__ float red[4];
  if (tid < 80) xrow[tid] = xs[(long)tok * 80 + tid];
  __syncthreads();
  const int c0 = tid, c1 = tid + 256;
  float y0 = bb[c0], y1 = bb[c1];
#pragma unroll 4
  for (int k = 0; k < 80; ++k) {
    const float xv = xrow[k];
    y0 = fmaf(xv, w[k * 512 + c0], y0);
    y1 = fmaf(xv, w[k * 512 + c1], y1);
  }
  const float mean = blocksum(y0 + y1, red, tid) * (1.0f / 512.0f);
  const float d0 = y0 - mean, d1 = y1 - mean;
  const float var = blocksum(d0 * d0 + d1 * d1, red, tid) * (1.0f / 512.0f);
  const float inv = rsqrtf(var + 1e-12f);
  const float r0 = fmaxf(d0 * inv * g[c0] + beta[c0], 0.0f);
  const float r1 = fmaxf(d1 * inv * g[c1] + beta[c1], 0.0f);
  const int t = tok & 1023;
  const float e0 = (float)(c0 & ~1) * (-9.210340371976184f / 512.0f);
  const float e1 = (float)(c1 & ~1) * (-9.210340371976184f / 512.0f);
  const float a0 = (float)t * __expf(e0);
  const float a1 = (float)t * __expf(e1);
  const float pe0 = (c0 & 1) ? cosf(a0) : sinf(a0);
  const float pe1 = (c1 & 1) ? cosf(a1) : sinf(a1);
  xout[(long)tok * 512 + c0] = r0 * 22.627416997969522f + pe0;
  xout[(long)tok * 512 + c1] = r1 * 22.627416997969522f + pe1;
}

// ---------------- LayerNorm over D=512, one block per row ----------------
template <int OUTF32>
__global__ __launch_bounds__(256) void ln_kernel(const float* __restrict__ x,
                                                 const float* __restrict__ g,
                                                 const float* __restrict__ bta,
                                                 void* __restrict__ outp) {
  const long row = blockIdx.x;
  const int tid = threadIdx.x;
  __shared__ float red[4];
  const float* xr = x + row * 512;
  const float v0 = xr[tid], v1 = xr[tid + 256];
  const float mean = blocksum(v0 + v1, red, tid) * (1.0f / 512.0f);
  const float d0 = v0 - mean, d1 = v1 - mean;
  const float var = blocksum(d0 * d0 + d1 * d1, red, tid) * (1.0f / 512.0f);
  const float inv = rsqrtf(var + 1e-12f);
  const float y0 = d0 * inv * g[tid] + bta[tid];
  const float y1 = d1 * inv * g[tid + 256] + bta[tid + 256];
  if (OUTF32) {
    float* o = (float*)outp;
    o[row * 512 + tid] = y0;
    o[row * 512 + tid + 256] = y1;
  } else {
    bf16* o = (bf16*)outp;
    o[row * 512 + tid] = __float2bfloat16(y0);
    o[row * 512 + tid + 256] = __float2bfloat16(y1);
  }
}

// ---------------- weight convert f32[K][N] -> bf16[N][K] (transposed) ----------------
__global__ __launch_bounds__(256) void trconv_kernel(const float* __restrict__ src,
                                                     bf16* __restrict__ dst, int K, int N,
                                                     long src_lstride, long dst_lstride) {
  __shared__ float tile[32][33];
  src += (long)blockIdx.z * src_lstride;
  dst += (long)blockIdx.z * dst_lstride;
  const int n0 = blockIdx.x * 32, k0 = blockIdx.y * 32;
  const int tx = threadIdx.x & 31, ty = threadIdx.x >> 5;
#pragma unroll
  for (int i = 0; i < 32; i += 8)
    tile[ty + i][tx] = src[(long)(k0 + ty + i) * N + n0 + tx];
  __syncthreads();
#pragma unroll
  for (int i = 0; i < 32; i += 8)
    dst[(long)(n0 + ty + i) * K + k0 + tx] = __float2bfloat16(tile[tx][ty + i]);
}

__global__ void biascat_kernel(const float* bq, const float* bk, const float* bv, float* o) {
  const int i = blockIdx.x * 256 + threadIdx.x;
  if (i >= 6 * 1536) return;
  const int l = i / 1536, n = i % 1536;
  o[i] = (n < 512) ? bq[l * 512 + n] : (n < 1024) ? bk[l * 512 + n - 512] : bv[l * 512 + n - 1024];
}

__global__ void maskout_kernel(const int* m, float* o, int n) {
  const int i = blockIdx.x * 256 + threadIdx.x;
  if (i < n) o[i] = m[i] ? 1.0f : 0.0f;
}

// ---------------- GEMM: C[M,N] = A[M,K](bf16) @ W^T[N,K](bf16) + bias ----------------
// MODE 0: write bf16 (optional RELU).  MODE 1: float out += (residual add).
template <int MODE, bool RELU>
__global__ __launch_bounds__(256) void gemm_kernel(const bf16* __restrict__ A,
                                                   const bf16* __restrict__ W,
                                                   const float* __restrict__ bias,
                                                   void* __restrict__ outp, int M, int N, int K) {
  __shared__ bf16 As[128 * 32];
  __shared__ bf16 Bs[128 * 32];
  const int tid = threadIdx.x, lane = tid & 63, wave = tid >> 6;
  const int m0 = blockIdx.x * 128, n0 = blockIdx.y * 128;
  const int wr = (wave >> 1) * 64, wc = (wave & 1) * 64;
  const bf16* ag = A + (long)(m0 + (tid >> 2)) * K + (tid & 3) * 8;
  const bf16* bg = W + (long)(n0 + (tid >> 2)) * K + (tid & 3) * 8;
  bf16* as0 = As + wave * 16 * 32;
  bf16* as1 = As + (64 + wave * 16) * 32;
  bf16* bs0 = Bs + wave * 16 * 32;
  bf16* bs1 = Bs + (64 + wave * 16) * 32;
  v4f acc[4][4] = {};
  const int frow = lane & 15, fch = lane >> 4;
  for (int k0 = 0; k0 < K; k0 += 32) {
    __syncthreads();
    gload16(ag + k0, as0);
    gload16(ag + (long)64 * K + k0, as1);
    gload16(bg + k0, bs0);
    gload16(bg + (long)64 * K + k0, bs1);
    __syncthreads();
    v8s af[4], bfv[4];
#pragma unroll
    for (int m = 0; m < 4; ++m)
      af[m] = *(const v8s*)(As + (wr + m * 16 + frow) * 32 + fch * 8);
#pragma unroll
    for (int n = 0; n < 4; ++n)
      bfv[n] = *(const v8s*)(Bs + (wc + n * 16 + frow) * 32 + fch * 8);
#pragma unroll
    for (int m = 0; m < 4; ++m)
#pragma unroll
      for (int n = 0; n < 4; ++n)
        acc[m][n] = mfma16(af[m], bfv[n], acc[m][n]);
  }
  float bv[4];
#pragma unroll
  for (int n = 0; n < 4; ++n) bv[n] = bias[n0 + wc + n * 16 + frow];
#pragma unroll
  for (int m = 0; m < 4; ++m) {
#pragma unroll
    for (int n = 0; n < 4; ++n) {
#pragma unroll
      for (int r = 0; r < 4; ++r) {
        const int row = m0 + wr + m * 16 + fch * 4 + r;
        const int col = n0 + wc + n * 16 + frow;
        float v = acc[m][n][r] + bv[n];
        if (RELU) v = fmaxf(v, 0.0f);
        if (MODE == 0)
          ((bf16*)outp)[(long)row * N + col] = __float2bfloat16(v);
        else
          ((float*)outp)[(long)row * N + col] += v;
      }
    }
  }
}

// ---------------- fused flash attention, 64-row Q tile, 64-key K tiles ----------------
// qkv: [8192][1536] bf16 (q | k | v).  chunked: block-causal CHUNK=16 LEFT=4 mask.
__global__ __launch_bounds__(256) void attn_kernel(const bf16* __restrict__ qkv,
                                                   bf16* __restrict__ aout, int chunked) {
  __shared__ char Qs[64 * 128];
  __shared__ char Ks[64 * 128];
  __shared__ char Vs[64 * 128];  // transposed: [dk][key]
  __shared__ char Ps[4][16 * 128];
  const int tid = threadIdx.x, lane = tid & 63, wave = tid >> 6;
  const int qt = blockIdx.x, bh = blockIdx.y;
  const long tb = (long)(bh >> 3) * 1024;
  const int hh = bh & 7;
  const int q0 = qt * 64;
  const int sr = tid >> 3, ss = tid & 7;
#pragma unroll
  for (int p = 0; p < 2; ++p) {
    const int rr = sr + p * 32;
    const uint4 d = *(const uint4*)(qkv + (tb + q0 + rr) * 1536 + hh * 64 + ss * 8);
    *(uint4*)(Qs + rr * 128 + ((ss * 16) ^ ((rr & 7) << 4))) = d;
  }
  __syncthreads();
  const int frow = lane & 15, fch = lane >> 4;
  const v8s qa0 = *(const v8s*)SWZ(Qs, wave * 16 + frow, fch * 16);
  const v8s qa1 = *(const v8s*)SWZ(Qs, wave * 16 + frow, 64 + fch * 16);
  v4f accv[4] = {};
  float m_run[4], l_run[4];
#pragma unroll
  for (int r = 0; r < 4; ++r) {
    m_run[r] = -1e30f;
    l_run[r] = 0.0f;
  }
  int kt0 = 0, kt1 = 16;
  if (chunked) {
    kt0 = qt > 0 ? qt - 1 : 0;
    kt1 = qt + 1;
  }
  for (int kt = kt0; kt < kt1; ++kt) {
    __syncthreads();
#pragma unroll
    for (int p = 0; p < 2; ++p) {
      const int rr = sr + p * 32;
      const long rowoff = (tb + kt * 64 + rr) * 1536 + hh * 64 + ss * 8;
      const uint4 kd = *(const uint4*)(qkv + rowoff + 512);
      *(uint4*)(Ks + rr * 128 + ((ss * 16) ^ ((rr & 7) << 4))) = kd;
      const uint4 vd = *(const uint4*)(qkv + rowoff + 1024);
      const bf16* ve = (const bf16*)&vd;
#pragma unroll
      for (int e = 0; e < 8; ++e) {
        const int dk = ss * 8 + e;
        *(bf16*)(Vs + dk * 128 + ((rr * 2) ^ ((dk & 7) << 4))) = ve[e];
      }
    }
    __syncthreads();
    v4f s4[4];
#pragma unroll
    for (int n = 0; n < 4; ++n) {
      const v8s kb0 = *(const v8s*)SWZ(Ks, n * 16 + frow, fch * 16);
      const v8s kb1 = *(const v8s*)SWZ(Ks, n * 16 + frow, 64 + fch * 16);
      v4f z = {0.f, 0.f, 0.f, 0.f};
      z = mfma16(qa0, kb0, z);
      z = mfma16(qa1, kb1, z);
      s4[n] = z * 0.125f;  // 1/sqrt(64)
    }
    if (chunked) {
#pragma unroll
      for (int n = 0; n < 4; ++n) {
        const int kb_ = (kt * 64 + n * 16 + frow) >> 4;
#pragma unroll
        for (int r = 0; r < 4; ++r) {
          const int qb_ = (q0 + wave * 16 + fch * 4 + r) >> 4;
          if (!(kb_ <= qb_ && qb_ - kb_ <= 4)) s4[n][r] = -1e30f;
        }
      }
    }
    float mnew[4], esc[4];
#pragma unroll
    for (int r = 0; r < 4; ++r) {
      float v = fmaxf(fmaxf(s4[0][r], s4[1][r]), fmaxf(s4[2][r], s4[3][r]));
      v = fmaxf(v, __shfl_xor(v, 1));
      v = fmaxf(v, __shfl_xor(v, 2));
      v = fmaxf(v, __shfl_xor(v, 4));
      v = fmaxf(v, __shfl_xor(v, 8));
      mnew[r] = fmaxf(m_run[r], v);
      esc[r] = __expf(m_run[r] - mnew[r]);
    }
#pragma unroll
    for (int n = 0; n < 4; ++n)
#pragma unroll
      for (int r = 0; r < 4; ++r) s4[n][r] = __expf(s4[n][r] - mnew[r]);
#pragma unroll
    for (int r = 0; r < 4; ++r) {
      float v = s4[0][r] + s4[1][r] + s4[2][r] + s4[3][r];
      v += __shfl_xor(v, 1);
      v += __shfl_xor(v, 2);
      v += __shfl_xor(v, 4);
      v += __shfl_xor(v, 8);
      l_run[r] = l_run[r] * esc[r] + v;
      m_run[r] = mnew[r];
    }
#pragma unroll
    for (int f = 0; f < 4; ++f)
#pragma unroll
      for (int r = 0; r < 4; ++r) accv[f][r] *= esc[r];
    char* Pw = Ps[wave];  // wave-private 16x64 P strip
#pragma unroll
    for (int n = 0; n < 4; ++n)
#pragma unroll
      for (int r = 0; r < 4; ++r) {
        const int rl = fch * 4 + r;
        *(bf16*)(Pw + rl * 128 + (((n * 16 + frow) * 2) ^ ((rl & 7) << 4))) =
            __float2bfloat16(s4[n][r]);
      }
    const v8s pa0 = *(const v8s*)SWZ(Pw, frow, fch * 16);
    const v8s pa1 = *(const v8s*)SWZ(Pw, frow, 64 + fch * 16);
#pragma unroll
    for (int f = 0; f < 4; ++f) {
      const v8s vb0 = *(const v8s*)SWZ(Vs, f * 16 + frow, fch * 16);
      const v8s vb1 = *(const v8s*)SWZ(Vs, f * 16 + frow, 64 + fch * 16);
      accv[f] = mfma16(pa0, vb0, accv[f]);
      accv[f] = mfma16(pa1, vb1, accv[f]);
    }
  }
#pragma unroll
  for (int f = 0; f < 4; ++f)
#pragma unroll
    for (int r = 0; r < 4; ++r) {
      const long row = tb + q0 + wave * 16 + fch * 4 + r;
      aout[row * 512 + hh * 64 + f * 16 + frow] = __float2bfloat16(accv[f][r] / l_run[r]);
    }
}

extern "C" void kernel_launch(void* const* d_in, const int* in_sizes, int n_in, void* d_out,
                              int out_size, void* d_ws, size_t ws_size, hipStream_t stream) {
  const float* xs = (const float*)d_in[0];
  const int* masks = (const int*)d_in[1];
  const float* emb_w = (const float*)d_in[2];
  const float* emb_b = (const float*)d_in[3];
  const float* emb_g = (const float*)d_in[4];
  const float* emb_beta = (const float*)d_in[5];
  const float* wq = (const float*)d_in[6];
  const float* bq = (const float*)d_in[7];
  const float* wk = (const float*)d_in[8];
  const float* bk = (const float*)d_in[9];
  const float* wv = (const float*)d_in[10];
  const float* bv = (const float*)d_in[11];
  const float* wo = (const float*)d_in[12];
  const float* bo = (const float*)d_in[13];
  const float* ln1g = (const float*)d_in[14];
  const float* ln1b = (const float*)d_in[15];
  const float* ln2g = (const float*)d_in[16];
  const float* ln2b = (const float*)d_in[17];
  const float* f1w = (const float*)d_in[18];
  const float* f1b = (const float*)d_in[19];
  const float* f2w = (const float*)d_in[20];
  const float* f2b = (const float*)d_in[21];
  const float* fing = (const float*)d_in[22];
  const float* finb = (const float*)d_in[23];

  char* ws = (char*)d_ws;
  size_t off = 0;
  auto alloc = [&](size_t bytes) -> void* {
    void* p = ws + off;
    off += (bytes + 255) & ~(size_t)255;
    return p;
  };
  bf16* Wqkv = (bf16*)alloc((size_t)6 * 1536 * 512 * 2);
  bf16* Wo = (bf16*)alloc((size_t)6 * 512 * 512 * 2);
  bf16* W1 = (bf16*)alloc((size_t)6 * 2048 * 512 * 2);
  bf16* W2 = (bf16*)alloc((size_t)6 * 512 * 2048 * 2);
  float* bqkv = (float*)alloc((size_t)6 * 1536 * 4);
  float* x = (float*)alloc((size_t)8192 * 512 * 4);
  bf16* h = (bf16*)alloc((size_t)8192 * 512 * 2);
  bf16* qkv = (bf16*)alloc((size_t)8192 * 1536 * 2);
  bf16* attn = (bf16*)alloc((size_t)8192 * 512 * 2);
  bf16* ff = qkv;  // aliases qkv+attn regions; FF activations live only after attention is consumed

  // weight prep: bf16 + transpose to [N][K]
  trconv_kernel<<<dim3(16, 16, 6), 256, 0, stream>>>(wq, Wqkv, 512, 512, (long)512 * 512,
                                                     (long)1536 * 512);
  trconv_kernel<<<dim3(16, 16, 6), 256, 0, stream>>>(wk, Wqkv + 512 * 512, 512, 512,
                                                     (long)512 * 512, (long)1536 * 512);
  trconv_kernel<<<dim3(16, 16, 6), 256, 0, stream>>>(wv, Wqkv + 1024 * 512, 512, 512,
                                                     (long)512 * 512, (long)1536 * 512);
  trconv_kernel<<<dim3(16, 16, 6), 256, 0, stream>>>(wo, Wo, 512, 512, (long)512 * 512,
                                                     (long)512 * 512);
  trconv_kernel<<<dim3(64, 16, 6), 256, 0, stream>>>(f1w, W1, 512, 2048, (long)512 * 2048,
                                                     (long)2048 * 512);
  trconv_kernel<<<dim3(16, 64, 6), 256, 0, stream>>>(f2w, W2, 2048, 512, (long)2048 * 512,
                                                     (long)512 * 2048);
  biascat_kernel<<<36, 256, 0, stream>>>(bq, bk, bv, bqkv);

  for (int stack = 0; stack < 2; ++stack) {
    embed_kernel<<<8192, 256, 0, stream>>>(xs, emb_w, emb_b, emb_g, emb_beta, x);
    for (int l = 0; l < 6; ++l) {
      ln_kernel<0><<<8192, 256, 0, stream>>>(x, ln1g + l * 512, ln1b + l * 512, h);
      gemm_kernel<0, false><<<dim3(64, 12), 256, 0, stream>>>(
          h, Wqkv + (size_t)l * 1536 * 512, bqkv + l * 1536, qkv, 8192, 1536, 512);
      attn_kernel<<<dim3(16, 64), 256, 0, stream>>>(qkv, attn, stack);
      gemm_kernel<1, false><<<dim3(64, 4), 256, 0, stream>>>(
          attn, Wo + (size_t)l * 512 * 512, bo + l * 512, x, 8192, 512, 512);
      ln_kernel<0><<<8192, 256, 0, stream>>>(x, ln2g + l * 512, ln2b + l * 512, h);
      gemm_kernel<0, true><<<dim3(64, 16), 256, 0, stream>>>(
          h, W1 + (size_t)l * 2048 * 512, f1b + l * 2048, ff, 8192, 2048, 512);
      gemm_kernel<1, false><<<dim3(64, 4), 256, 0, stream>>>(
          ff, W2 + (size_t)l * 512 * 2048, f2b + l * 512, x, 8192, 512, 2048);
    }
    ln_kernel<1><<<8192, 256, 0, stream>>>(x, fing, finb,
                                           (float*)d_out + (size_t)stack * 8192 * 512);
  }
  maskout_kernel<<<32, 256, 0, stream>>>(masks, (float*)d_out + (size_t)2 * 8192 * 512, 8192);
  (void)in_sizes;
  (void)n_in;
  (void)out_size;
  (void)ws_size;
}

// Round 3
// 2312.240 us; speedup vs baseline: 1.1681x; 1.1681x over previous
//
#include <hip/hip_runtime.h>
#include <hip/hip_bf16.h>
#include <cstdint>

typedef __hip_bfloat16 bf16;
typedef __attribute__((ext_vector_type(8))) short v8s;
typedef __attribute__((ext_vector_type(4))) float v4f;

// swizzled LDS address for 128B-row tiles: XOR 16B-slot bits with (row&7)  [guide G4]
#define SWZ(base, row, bytecol) ((base) + (row) * 128 + ((bytecol) ^ (((row) & 7) << 4)))
// P-strip row hash: uses both fch bits of rl=fch*4+r -> conflict-free P writes
#define HROW(t) ((((t) >> 2) << 1) | ((t) & 1))

__device__ __forceinline__ void gload16(const void* g, void* l) {
  __builtin_amdgcn_global_load_lds((__attribute__((address_space(1))) void*)g,
                                   (__attribute__((address_space(3))) void*)l, 16, 0, 0);
}

__device__ __forceinline__ v4f mfma16(v8s a, v8s b, v4f c) {
  return __builtin_amdgcn_mfma_f32_16x16x32_bf16(a, b, c, 0, 0, 0);
}

__device__ __forceinline__ float blocksum(float v, float* red, int tid) {
#pragma unroll
  for (int o = 32; o > 0; o >>= 1) v += __shfl_xor(v, o);
  if ((tid & 63) == 0) red[tid >> 6] = v;
  __syncthreads();
  float r = red[0] + red[1] + red[2] + red[3];
  __syncthreads();
  return r;
}

// ---------------- embed: xs@W + b -> LN -> relu -> posenc ----------------
__global__ __launch_bounds__(256) void embed_kernel(
    const float* __restrict__ xs, const float* __restrict__ w, const float* __restrict__ bb,
    const float* __restrict__ g, const float* __restrict__ beta, float* __restrict__ xout) {
  const int tok = blockIdx.x;      // may span both stacks (merged)
  const int srct = tok & 8191;     // xs row
  const int tid = threadIdx.x;
  __shared__ float xrow[80];
  __shared__ float red[4];
  if (tid < 80) xrow[tid] = xs[(long)srct * 80 + tid];
  __syncthreads();
  const int c0 = tid, c1 = tid + 256;
  float y0 = bb[c0], y1 = bb[c1];
#pragma unroll 4
  for (int k = 0; k < 80; ++k) {
    const float xv = xrow[k];
    y0 = fmaf(xv, w[k * 512 + c0], y0);
    y1 = fmaf(xv, w[k * 512 + c1], y1);
  }
  const float mean = blocksum(y0 + y1, red, tid) * (1.0f / 512.0f);
  const float d0 = y0 - mean, d1 = y1 - mean;
  const float var = blocksum(d0 * d0 + d1 * d1, red, tid) * (1.0f / 512.0f);
  const float inv = rsqrtf(var + 1e-12f);
  const float r0 = fmaxf(d0 * inv * g[c0] + beta[c0], 0.0f);
  const float r1 = fmaxf(d1 * inv * g[c1] + beta[c1], 0.0f);
  const int t = tok & 1023;
  const float e0 = (float)(c0 & ~1) * (-9.210340371976184f / 512.0f);
  const float e1 = (float)(c1 & ~1) * (-9.210340371976184f / 512.0f);
  const float a0 = (float)t * __expf(e0);
  const float a1 = (float)t * __expf(e1);
  const float pe0 = (c0 & 1) ? cosf(a0) : sinf(a0);
  const float pe1 = (c1 & 1) ? cosf(a1) : sinf(a1);
  xout[(long)tok * 512 + c0] = r0 * 22.627416997969522f + pe0;
  xout[(long)tok * 512 + c1] = r1 * 22.627416997969522f + pe1;
}

// ---------------- plain LayerNorm (layer-0 ln1 only) ----------------
__global__ __launch_bounds__(256) void ln_kernel(const float* __restrict__ x,
                                                 const float* __restrict__ g,
                                                 const float* __restrict__ bta,
                                                 bf16* __restrict__ o) {
  const long row = blockIdx.x;
  const int tid = threadIdx.x;
  __shared__ float red[4];
  const float* xr = x + row * 512;
  const float v0 = xr[tid], v1 = xr[tid + 256];
  const float mean = blocksum(v0 + v1, red, tid) * (1.0f / 512.0f);
  const float d0 = v0 - mean, d1 = v1 - mean;
  const float var = blocksum(d0 * d0 + d1 * d1, red, tid) * (1.0f / 512.0f);
  const float inv = rsqrtf(var + 1e-12f);
  o[row * 512 + tid] = __float2bfloat16(d0 * inv * g[tid] + bta[tid]);
  o[row * 512 + tid + 256] = __float2bfloat16(d1 * inv * g[tid + 256] + bta[tid + 256]);
}

// ---------------- fused residual add + LayerNorm ----------------
// x += y (bf16); out = LN(x).  FINAL: out is f32 d_out and x not written back.
template <int FINAL>
__global__ __launch_bounds__(256) void add_ln_kernel(float* __restrict__ x,
                                                     const bf16* __restrict__ y,
                                                     const float* __restrict__ g,
                                                     const float* __restrict__ bta,
                                                     void* __restrict__ outp) {
  const long row = blockIdx.x;
  const int tid = threadIdx.x;
  __shared__ float red[4];
  const float v0 = x[row * 512 + tid] + __bfloat162float(y[row * 512 + tid]);
  const float v1 = x[row * 512 + tid + 256] + __bfloat162float(y[row * 512 + tid + 256]);
  if (!FINAL) {
    x[row * 512 + tid] = v0;
    x[row * 512 + tid + 256] = v1;
  }
  const float mean = blocksum(v0 + v1, red, tid) * (1.0f / 512.0f);
  const float d0 = v0 - mean, d1 = v1 - mean;
  const float var = blocksum(d0 * d0 + d1 * d1, red, tid) * (1.0f / 512.0f);
  const float inv = rsqrtf(var + 1e-12f);
  const float y0 = d0 * inv * g[tid] + bta[tid];
  const float y1 = d1 * inv * g[tid + 256] + bta[tid + 256];
  if (FINAL) {
    float* o = (float*)outp;
    o[row * 512 + tid] = y0;
    o[row * 512 + tid + 256] = y1;
  } else {
    bf16* o = (bf16*)outp;
    o[row * 512 + tid] = __float2bfloat16(y0);
    o[row * 512 + tid + 256] = __float2bfloat16(y1);
  }
}

// ---------------- weight convert f32[K][N] -> bf16[N][K] (transposed) ----------------
__global__ __launch_bounds__(256) void trconv_kernel(const float* __restrict__ src,
                                                     bf16* __restrict__ dst, int K, int N,
                                                     long src_lstride, long dst_lstride) {
  __shared__ float tile[32][33];
  src += (long)blockIdx.z * src_lstride;
  dst += (long)blockIdx.z * dst_lstride;
  const int n0 = blockIdx.x * 32, k0 = blockIdx.y * 32;
  const int tx = threadIdx.x & 31, ty = threadIdx.x >> 5;
#pragma unroll
  for (int i = 0; i < 32; i += 8)
    tile[ty + i][tx] = src[(long)(k0 + ty + i) * N + n0 + tx];
  __syncthreads();
#pragma unroll
  for (int i = 0; i < 32; i += 8)
    dst[(long)(n0 + ty + i) * K + k0 + tx] = __float2bfloat16(tile[tx][ty + i]);
}

__global__ void biascat_kernel(const float* bq, const float* bk, const float* bv, float* o) {
  const int i = blockIdx.x * 256 + threadIdx.x;
  if (i >= 6 * 1536) return;
  const int l = i / 1536, n = i % 1536;
  o[i] = (n < 512) ? bq[l * 512 + n] : (n < 1024) ? bk[l * 512 + n - 512] : bv[l * 512 + n - 1024];
}

__global__ void maskout_kernel(const int* m, float* o, int n) {
  const int i = blockIdx.x * 256 + threadIdx.x;
  if (i < n) o[i] = m[i] ? 1.0f : 0.0f;
}

// ---------------- GEMM: C[M,N](bf16) = A[M,K](bf16) @ W^T[N,K](bf16) + bias ----------------
template <bool RELU>
__global__ __launch_bounds__(256) void gemm_kernel(const bf16* __restrict__ A,
                                                   const bf16* __restrict__ W,
                                                   const float* __restrict__ bias,
                                                   bf16* __restrict__ outp, int M, int N, int K) {
  __shared__ bf16 As[128 * 32];
  __shared__ bf16 Bs[128 * 32];
  const int tid = threadIdx.x, lane = tid & 63, wave = tid >> 6;
  const int m0 = blockIdx.x * 128, n0 = blockIdx.y * 128;
  const int wr = (wave >> 1) * 64, wc = (wave & 1) * 64;
  const bf16* ag = A + (long)(m0 + (tid >> 2)) * K + (tid & 3) * 8;
  const bf16* bg = W + (long)(n0 + (tid >> 2)) * K + (tid & 3) * 8;
  bf16* as0 = As + wave * 16 * 32;
  bf16* as1 = As + (64 + wave * 16) * 32;
  bf16* bs0 = Bs + wave * 16 * 32;
  bf16* bs1 = Bs + (64 + wave * 16) * 32;
  v4f acc[4][4] = {};
  const int frow = lane & 15, fch = lane >> 4;
  for (int k0 = 0; k0 < K; k0 += 32) {
    __syncthreads();
    gload16(ag + k0, as0);
    gload16(ag + (long)64 * K + k0, as1);
    gload16(bg + k0, bs0);
    gload16(bg + (long)64 * K + k0, bs1);
    __syncthreads();
    v8s af[4], bfv[4];
#pragma unroll
    for (int m = 0; m < 4; ++m)
      af[m] = *(const v8s*)(As + (wr + m * 16 + frow) * 32 + fch * 8);
#pragma unroll
    for (int n = 0; n < 4; ++n)
      bfv[n] = *(const v8s*)(Bs + (wc + n * 16 + frow) * 32 + fch * 8);
#pragma unroll
    for (int m = 0; m < 4; ++m)
#pragma unroll
      for (int n = 0; n < 4; ++n)
        acc[m][n] = mfma16(af[m], bfv[n], acc[m][n]);
  }
  float bv[4];
#pragma unroll
  for (int n = 0; n < 4; ++n) bv[n] = bias[n0 + wc + n * 16 + frow];
#pragma unroll
  for (int m = 0; m < 4; ++m) {
#pragma unroll
    for (int n = 0; n < 4; ++n) {
#pragma unroll
      for (int r = 0; r < 4; ++r) {
        const int row = m0 + wr + m * 16 + fch * 4 + r;
        const int col = n0 + wc + n * 16 + frow;
        float v = acc[m][n][r] + bv[n];
        if (RELU) v = fmaxf(v, 0.0f);
        outp[(long)row * N + col] = __float2bfloat16(v);
      }
    }
  }
}

// ---------------- fused flash attention, 64-row Q tile, 64-key K tiles ----------------
// qkv: [rows][1536] bf16 (q | k | v).  chunked = chunk0 + blockIdx.z (nonzero -> CHUNK=16 LEFT=4).
__global__ __launch_bounds__(256) void attn_kernel(const bf16* __restrict__ qkv,
                                                   bf16* __restrict__ aout, int chunk0) {
  __shared__ char Qs[64 * 128];
  __shared__ char Ks[64 * 128];
  __shared__ char Vs[64 * 128];  // transposed: [dk][key], SWZ layout
  __shared__ char Ps[4][16 * 128];
  const int tid = threadIdx.x, lane = tid & 63, wave = tid >> 6;
  const int qt = blockIdx.x, bh = blockIdx.y;
  const int chunked = chunk0 + (int)blockIdx.z;
  const long tb = (long)blockIdx.z * 8192 + (long)(bh >> 3) * 1024;
  const int hh = bh & 7;
  const int q0 = qt * 64;
  const int sr = tid >> 3, ss = tid & 7;
#pragma unroll
  for (int p = 0; p < 2; ++p) {
    const int rr = sr + p * 32;
    const uint4 d = *(const uint4*)(qkv + (tb + q0 + rr) * 1536 + hh * 64 + ss * 8);
    *(uint4*)(Qs + rr * 128 + ((ss * 16) ^ ((rr & 7) << 4))) = d;
  }
  __syncthreads();
  const int frow = lane & 15, fch = lane >> 4;
  const v8s qa0 = *(const v8s*)SWZ(Qs, wave * 16 + frow, fch * 16);
  const v8s qa1 = *(const v8s*)SWZ(Qs, wave * 16 + frow, 64 + fch * 16);
  v4f accv[4] = {};
  float m_run[4], l_run[4];
#pragma unroll
  for (int r = 0; r < 4; ++r) {
    m_run[r] = -1e30f;
    l_run[r] = 0.0f;
  }
  int kt0 = 0, kt1 = 16;
  if (chunked) {
    kt0 = qt > 0 ? qt - 1 : 0;
    kt1 = qt + 1;
  }
  for (int kt = kt0; kt < kt1; ++kt) {
    __syncthreads();
#pragma unroll
    for (int p = 0; p < 2; ++p) {
      const int rr = sr + p * 32;
      const long rowoff = (tb + kt * 64 + rr) * 1536 + hh * 64 + ss * 8;
      const uint4 kd = *(const uint4*)(qkv + rowoff + 512);
      *(uint4*)(Ks + rr * 128 + ((ss * 16) ^ ((rr & 7) << 4))) = kd;
      const uint4 vd = *(const uint4*)(qkv + rowoff + 1024);
      const bf16* ve = (const bf16*)&vd;
#pragma unroll
      for (int e = 0; e < 8; ++e) {
        const int ee = (e + ss) & 7;  // rotate by ss: banks spread across lanes
        const int dk = ss * 8 + ee;
        *(bf16*)(Vs + dk * 128 + ((rr * 2) ^ ((dk & 7) << 4))) = ve[ee];
      }
    }
    __syncthreads();
    v4f s4[4];
#pragma unroll
    for (int n = 0; n < 4; ++n) {
      const v8s kb0 = *(const v8s*)SWZ(Ks, n * 16 + frow, fch * 16);
      const v8s kb1 = *(const v8s*)SWZ(Ks, n * 16 + frow, 64 + fch * 16);
      v4f z = {0.f, 0.f, 0.f, 0.f};
      z = mfma16(qa0, kb0, z);
      z = mfma16(qa1, kb1, z);
      s4[n] = z * 0.125f;  // 1/sqrt(64)
    }
    if (chunked) {
#pragma unroll
      for (int n = 0; n < 4; ++n) {
        const int kb_ = (kt * 64 + n * 16 + frow) >> 4;
#pragma unroll
        for (int r = 0; r < 4; ++r) {
          const int qb_ = (q0 + wave * 16 + fch * 4 + r) >> 4;
          if (!(kb_ <= qb_ && qb_ - kb_ <= 4)) s4[n][r] = -1e30f;
        }
      }
    }
    float mnew[4], esc[4];
#pragma unroll
    for (int r = 0; r < 4; ++r) {
      float v = fmaxf(fmaxf(s4[0][r], s4[1][r]), fmaxf(s4[2][r], s4[3][r]));
      v = fmaxf(v, __shfl_xor(v, 1));
      v = fmaxf(v, __shfl_xor(v, 2));
      v = fmaxf(v, __shfl_xor(v, 4));
      v = fmaxf(v, __shfl_xor(v, 8));
      mnew[r] = fmaxf(m_run[r], v);
      esc[r] = __expf(m_run[r] - mnew[r]);
    }
#pragma unroll
    for (int n = 0; n < 4; ++n)
#pragma unroll
      for (int r = 0; r < 4; ++r) s4[n][r] = __expf(s4[n][r] - mnew[r]);
#pragma unroll
    for (int r = 0; r < 4; ++r) {
      float v = s4[0][r] + s4[1][r] + s4[2][r] + s4[3][r];
      v += __shfl_xor(v, 1);
      v += __shfl_xor(v, 2);
      v += __shfl_xor(v, 4);
      v += __shfl_xor(v, 8);
      l_run[r] = l_run[r] * esc[r] + v;
      m_run[r] = mnew[r];
    }
#pragma unroll
    for (int f = 0; f < 4; ++f)
#pragma unroll
      for (int r = 0; r < 4; ++r) accv[f][r] *= esc[r];
    char* Pw = Ps[wave];  // wave-private 16x64 P strip, HROW swizzle
#pragma unroll
    for (int n = 0; n < 4; ++n)
#pragma unroll
      for (int r = 0; r < 4; ++r) {
        const int rl = fch * 4 + r;
        *(bf16*)(Pw + rl * 128 + (((n * 16 + frow) * 2) ^ (HROW(rl) << 4))) =
            __float2bfloat16(s4[n][r]);
      }
    const v8s pa0 = *(const v8s*)(Pw + frow * 128 + ((fch * 16) ^ (HROW(frow) << 4)));
    const v8s pa1 = *(const v8s*)(Pw + frow * 128 + ((64 + fch * 16) ^ (HROW(frow) << 4)));
#pragma unroll
    for (int f = 0; f < 4; ++f) {
      const v8s vb0 = *(const v8s*)SWZ(Vs, f * 16 + frow, fch * 16);
      const v8s vb1 = *(const v8s*)SWZ(Vs, f * 16 + frow, 64 + fch * 16);
      accv[f] = mfma16(pa0, vb0, accv[f]);
      accv[f] = mfma16(pa1, vb1, accv[f]);
    }
  }
#pragma unroll
  for (int f = 0; f < 4; ++f)
#pragma unroll
    for (int r = 0; r < 4; ++r) {
      const long row = tb + q0 + wave * 16 + fch * 4 + r;
      aout[row * 512 + hh * 64 + f * 16 + frow] = __float2bfloat16(accv[f][r] / l_run[r]);
    }
}

struct Bufs {
  bf16 *Wqkv, *Wo, *W1, *W2;
  float* bqkv;
  float* x;
  bf16 *h, *qkv, *attn;
  size_t need;
};

static Bufs make_layout(char* ws, long rows) {
  size_t off = 0;
  auto al = [&](size_t b) -> void* {
    void* p = ws + off;
    off += (b + 255) & ~(size_t)255;
    return p;
  };
  Bufs B;
  B.Wqkv = (bf16*)al((size_t)6 * 1536 * 512 * 2);
  B.Wo = (bf16*)al((size_t)6 * 512 * 512 * 2);
  B.W1 = (bf16*)al((size_t)6 * 2048 * 512 * 2);
  B.W2 = (bf16*)al((size_t)6 * 512 * 2048 * 2);
  B.bqkv = (float*)al((size_t)6 * 1536 * 4);
  B.x = (float*)al((size_t)rows * 512 * 4);
  B.h = (bf16*)al((size_t)rows * 512 * 2);
  B.qkv = (bf16*)al((size_t)rows * 1536 * 2);   // qkv and attn contiguous:
  B.attn = (bf16*)al((size_t)rows * 512 * 2);   // ff[rows][2048] aliases both
  B.need = off;
  return B;
}

extern "C" void kernel_launch(void* const* d_in, const int* in_sizes, int n_in, void* d_out,
                              int out_size, void* d_ws, size_t ws_size, hipStream_t stream) {
  const float* xs = (const float*)d_in[0];
  const int* masks = (const int*)d_in[1];
  const float* emb_w = (const float*)d_in[2];
  const float* emb_b = (const float*)d_in[3];
  const float* emb_g = (const float*)d_in[4];
  const float* emb_beta = (const float*)d_in[5];
  const float* wq = (const float*)d_in[6];
  const float* bq = (const float*)d_in[7];
  const float* wk = (const float*)d_in[8];
  const float* bk = (const float*)d_in[9];
  const float* wv = (const float*)d_in[10];
  const float* bv = (const float*)d_in[11];
  const float* wo = (const float*)d_in[12];
  const float* bo = (const float*)d_in[13];
  const float* ln1g = (const float*)d_in[14];
  const float* ln1b = (const float*)d_in[15];
  const float* ln2g = (const float*)d_in[16];
  const float* ln2b = (const float*)d_in[17];
  const float* f1w = (const float*)d_in[18];
  const float* f1b = (const float*)d_in[19];
  const float* f2w = (const float*)d_in[20];
  const float* f2b = (const float*)d_in[21];
  const float* fing = (const float*)d_in[22];
  const float* finb = (const float*)d_in[23];

  char* ws = (char*)d_ws;
  Bufs bm = make_layout(ws, 16384);
  const bool merged = bm.need <= ws_size;
  Bufs b = merged ? bm : make_layout(ws, 8192);
  const long rows = merged ? 16384 : 8192;
  const int npass = merged ? 1 : 2;
  const int mg = (int)(rows / 128);   // gemm grid.x
  const int zdim = (int)(rows / 8192);

  // weight prep: bf16 + transpose to [N][K]
  trconv_kernel<<<dim3(16, 16, 6), 256, 0, stream>>>(wq, b.Wqkv, 512, 512, (long)512 * 512,
                                                     (long)1536 * 512);
  trconv_kernel<<<dim3(16, 16, 6), 256, 0, stream>>>(wk, b.Wqkv + 512 * 512, 512, 512,
                                                     (long)512 * 512, (long)1536 * 512);
  trconv_kernel<<<dim3(16, 16, 6), 256, 0, stream>>>(wv, b.Wqkv + 1024 * 512, 512, 512,
                                                     (long)512 * 512, (long)1536 * 512);
  trconv_kernel<<<dim3(16, 16, 6), 256, 0, stream>>>(wo, b.Wo, 512, 512, (long)512 * 512,
                                                     (long)512 * 512);
  trconv_kernel<<<dim3(64, 16, 6), 256, 0, stream>>>(f1w, b.W1, 512, 2048, (long)512 * 2048,
                                                     (long)2048 * 512);
  trconv_kernel<<<dim3(16, 64, 6), 256, 0, stream>>>(f2w, b.W2, 2048, 512, (long)2048 * 512,
                                                     (long)512 * 2048);
  biascat_kernel<<<36, 256, 0, stream>>>(bq, bk, bv, b.bqkv);

  for (int pass = 0; pass < npass; ++pass) {
    embed_kernel<<<(int)rows, 256, 0, stream>>>(xs, emb_w, emb_b, emb_g, emb_beta, b.x);
    ln_kernel<<<(int)rows, 256, 0, stream>>>(b.x, ln1g, ln1b, b.h);
    for (int l = 0; l < 6; ++l) {
      gemm_kernel<false><<<dim3(mg, 12), 256, 0, stream>>>(
          b.h, b.Wqkv + (size_t)l * 1536 * 512, b.bqkv + l * 1536, b.qkv, (int)rows, 1536, 512);
      attn_kernel<<<dim3(16, 64, zdim), 256, 0, stream>>>(b.qkv, b.attn, merged ? 0 : pass);
      gemm_kernel<false><<<dim3(mg, 4), 256, 0, stream>>>(
          b.attn, b.Wo + (size_t)l * 512 * 512, bo + l * 512, b.h, (int)rows, 512, 512);
      add_ln_kernel<0><<<(int)rows, 256, 0, stream>>>(b.x, b.h, ln2g + l * 512, ln2b + l * 512,
                                                      b.h);
      gemm_kernel<true><<<dim3(mg, 16), 256, 0, stream>>>(
          b.h, b.W1 + (size_t)l * 2048 * 512, f1b + l * 2048, b.qkv /*ff*/, (int)rows, 2048, 512);
      gemm_kernel<false><<<dim3(mg, 4), 256, 0, stream>>>(
          b.qkv /*ff*/, b.W2 + (size_t)l * 512 * 2048, f2b + l * 512, b.h, (int)rows, 512, 2048);
      if (l < 5)
        add_ln_kernel<0><<<(int)rows, 256, 0, stream>>>(b.x, b.h, ln1g + (l + 1) * 512,
                                                        ln1b + (l + 1) * 512, b.h);
      else
        add_ln_kernel<1><<<(int)rows, 256, 0, stream>>>(
            b.x, b.h, fing, finb, (float*)d_out + (size_t)pass * 8192 * 512);
    }
  }
  maskout_kernel<<<32, 256, 0, stream>>>(masks, (float*)d_out + (size_t)2 * 8192 * 512, 8192);
  (void)in_sizes;
  (void)n_in;
  (void)out_size;
}

// Round 4
// 1786.154 us; speedup vs baseline: 1.5121x; 1.2945x over previous
//
#include <hip/hip_runtime.h>
#include <hip/hip_bf16.h>
#include <cstdint>

typedef __hip_bfloat16 bf16;
typedef __attribute__((ext_vector_type(8))) short v8s;
typedef __attribute__((ext_vector_type(4))) float v4f;

// swizzled LDS address for 128B-row tiles: XOR 16B-slot bits with (row&7)  [guide G4]
#define SWZ(base, row, bytecol) ((base) + (row) * 128 + ((bytecol) ^ (((row) & 7) << 4)))
// P-strip row hash: uses both fch bits of rl=fch*4+r -> conflict-free P writes
#define HROW(t) ((((t) >> 2) << 1) | ((t) & 1))

__device__ __forceinline__ void gload16(const void* g, void* l) {
  __builtin_amdgcn_global_load_lds((__attribute__((address_space(1))) void*)g,
                                   (__attribute__((address_space(3))) void*)l, 16, 0, 0);
}

__device__ __forceinline__ v4f mfma16(v8s a, v8s b, v4f c) {
  return __builtin_amdgcn_mfma_f32_16x16x32_bf16(a, b, c, 0, 0, 0);
}

__device__ __forceinline__ float blocksum(float v, float* red, int tid) {
#pragma unroll
  for (int o = 32; o > 0; o >>= 1) v += __shfl_xor(v, o);
  if ((tid & 63) == 0) red[tid >> 6] = v;
  __syncthreads();
  float r = red[0] + red[1] + red[2] + red[3];
  __syncthreads();
  return r;
}

// ---------------- embed: xs@W + b -> LN -> relu -> posenc ----------------
__global__ __launch_bounds__(256) void embed_kernel(
    const float* __restrict__ xs, const float* __restrict__ w, const float* __restrict__ bb,
    const float* __restrict__ g, const float* __restrict__ beta, float* __restrict__ xout) {
  const int tok = blockIdx.x;      // may span both stacks (merged)
  const int srct = tok & 8191;     // xs row
  const int tid = threadIdx.x;
  __shared__ float xrow[80];
  __shared__ float red[4];
  if (tid < 80) xrow[tid] = xs[(long)srct * 80 + tid];
  __syncthreads();
  const int c0 = tid, c1 = tid + 256;
  float y0 = bb[c0], y1 = bb[c1];
#pragma unroll 4
  for (int k = 0; k < 80; ++k) {
    const float xv = xrow[k];
    y0 = fmaf(xv, w[k * 512 + c0], y0);
    y1 = fmaf(xv, w[k * 512 + c1], y1);
  }
  const float mean = blocksum(y0 + y1, red, tid) * (1.0f / 512.0f);
  const float d0 = y0 - mean, d1 = y1 - mean;
  const float var = blocksum(d0 * d0 + d1 * d1, red, tid) * (1.0f / 512.0f);
  const float inv = rsqrtf(var + 1e-12f);
  const float r0 = fmaxf(d0 * inv * g[c0] + beta[c0], 0.0f);
  const float r1 = fmaxf(d1 * inv * g[c1] + beta[c1], 0.0f);
  const int t = tok & 1023;
  const float e0 = (float)(c0 & ~1) * (-9.210340371976184f / 512.0f);
  const float e1 = (float)(c1 & ~1) * (-9.210340371976184f / 512.0f);
  const float a0 = (float)t * __expf(e0);
  const float a1 = (float)t * __expf(e1);
  const float pe0 = (c0 & 1) ? cosf(a0) : sinf(a0);
  const float pe1 = (c1 & 1) ? cosf(a1) : sinf(a1);
  xout[(long)tok * 512 + c0] = r0 * 22.627416997969522f + pe0;
  xout[(long)tok * 512 + c1] = r1 * 22.627416997969522f + pe1;
}

// ---------------- plain LayerNorm (layer-0 ln1 only) ----------------
__global__ __launch_bounds__(256) void ln_kernel(const float* __restrict__ x,
                                                 const float* __restrict__ g,
                                                 const float* __restrict__ bta,
                                                 bf16* __restrict__ o) {
  const long row = blockIdx.x;
  const int tid = threadIdx.x;
  __shared__ float red[4];
  const float* xr = x + row * 512;
  const float v0 = xr[tid], v1 = xr[tid + 256];
  const float mean = blocksum(v0 + v1, red, tid) * (1.0f / 512.0f);
  const float d0 = v0 - mean, d1 = v1 - mean;
  const float var = blocksum(d0 * d0 + d1 * d1, red, tid) * (1.0f / 512.0f);
  const float inv = rsqrtf(var + 1e-12f);
  o[row * 512 + tid] = __float2bfloat16(d0 * inv * g[tid] + bta[tid]);
  o[row * 512 + tid + 256] = __float2bfloat16(d1 * inv * g[tid + 256] + bta[tid + 256]);
}

// ---------------- fused residual add + LayerNorm ----------------
// x += y (bf16); out = LN(x).  FINAL: out is f32 d_out and x not written back.
template <int FINAL>
__global__ __launch_bounds__(256) void add_ln_kernel(float* __restrict__ x,
                                                     const bf16* __restrict__ y,
                                                     const float* __restrict__ g,
                                                     const float* __restrict__ bta,
                                                     void* __restrict__ outp) {
  const long row = blockIdx.x;
  const int tid = threadIdx.x;
  __shared__ float red[4];
  const float v0 = x[row * 512 + tid] + __bfloat162float(y[row * 512 + tid]);
  const float v1 = x[row * 512 + tid + 256] + __bfloat162float(y[row * 512 + tid + 256]);
  if (!FINAL) {
    x[row * 512 + tid] = v0;
    x[row * 512 + tid + 256] = v1;
  }
  const float mean = blocksum(v0 + v1, red, tid) * (1.0f / 512.0f);
  const float d0 = v0 - mean, d1 = v1 - mean;
  const float var = blocksum(d0 * d0 + d1 * d1, red, tid) * (1.0f / 512.0f);
  const float inv = rsqrtf(var + 1e-12f);
  const float y0 = d0 * inv * g[tid] + bta[tid];
  const float y1 = d1 * inv * g[tid + 256] + bta[tid + 256];
  if (FINAL) {
    float* o = (float*)outp;
    o[row * 512 + tid] = y0;
    o[row * 512 + tid + 256] = y1;
  } else {
    bf16* o = (bf16*)outp;
    o[row * 512 + tid] = __float2bfloat16(y0);
    o[row * 512 + tid + 256] = __float2bfloat16(y1);
  }
}

// ---------------- weight convert f32[K][N] -> bf16[N][K] (transposed) ----------------
__global__ __launch_bounds__(256) void trconv_kernel(const float* __restrict__ src,
                                                     bf16* __restrict__ dst, int K, int N,
                                                     long src_lstride, long dst_lstride) {
  __shared__ float tile[32][33];
  src += (long)blockIdx.z * src_lstride;
  dst += (long)blockIdx.z * dst_lstride;
  const int n0 = blockIdx.x * 32, k0 = blockIdx.y * 32;
  const int tx = threadIdx.x & 31, ty = threadIdx.x >> 5;
#pragma unroll
  for (int i = 0; i < 32; i += 8)
    tile[ty + i][tx] = src[(long)(k0 + ty + i) * N + n0 + tx];
  __syncthreads();
#pragma unroll
  for (int i = 0; i < 32; i += 8)
    dst[(long)(n0 + ty + i) * K + k0 + tx] = __float2bfloat16(tile[tx][ty + i]);
}

__global__ void biascat_kernel(const float* bq, const float* bk, const float* bv, float* o) {
  const int i = blockIdx.x * 256 + threadIdx.x;
  if (i >= 6 * 1536) return;
  const int l = i / 1536, n = i % 1536;
  o[i] = (n < 512) ? bq[l * 512 + n] : (n < 1024) ? bk[l * 512 + n - 512] : bv[l * 512 + n - 1024];
}

__global__ void maskout_kernel(const int* m, float* o, int n) {
  const int i = blockIdx.x * 256 + threadIdx.x;
  if (i < n) o[i] = m[i] ? 1.0f : 0.0f;
}

// ---------------- GEMM: C[M,N](bf16) = A[M,K](bf16) @ W^T[N,K](bf16) + bias ----------------
template <bool RELU>
__global__ __launch_bounds__(256) void gemm_kernel(const bf16* __restrict__ A,
                                                   const bf16* __restrict__ W,
                                                   const float* __restrict__ bias,
                                                   bf16* __restrict__ outp, int M, int N, int K) {
  __shared__ bf16 As[128 * 32];
  __shared__ bf16 Bs[128 * 32];
  const int tid = threadIdx.x, lane = tid & 63, wave = tid >> 6;
  const int m0 = blockIdx.x * 128, n0 = blockIdx.y * 128;
  const int wr = (wave >> 1) * 64, wc = (wave & 1) * 64;
  const bf16* ag = A + (long)(m0 + (tid >> 2)) * K + (tid & 3) * 8;
  const bf16* bg = W + (long)(n0 + (tid >> 2)) * K + (tid & 3) * 8;
  bf16* as0 = As + wave * 16 * 32;
  bf16* as1 = As + (64 + wave * 16) * 32;
  bf16* bs0 = Bs + wave * 16 * 32;
  bf16* bs1 = Bs + (64 + wave * 16) * 32;
  v4f acc[4][4] = {};
  const int frow = lane & 15, fch = lane >> 4;
  for (int k0 = 0; k0 < K; k0 += 32) {
    __syncthreads();
    gload16(ag + k0, as0);
    gload16(ag + (long)64 * K + k0, as1);
    gload16(bg + k0, bs0);
    gload16(bg + (long)64 * K + k0, bs1);
    __syncthreads();
    v8s af[4], bfv[4];
#pragma unroll
    for (int m = 0; m < 4; ++m)
      af[m] = *(const v8s*)(As + (wr + m * 16 + frow) * 32 + fch * 8);
#pragma unroll
    for (int n = 0; n < 4; ++n)
      bfv[n] = *(const v8s*)(Bs + (wc + n * 16 + frow) * 32 + fch * 8);
#pragma unroll
    for (int m = 0; m < 4; ++m)
#pragma unroll
      for (int n = 0; n < 4; ++n)
        acc[m][n] = mfma16(af[m], bfv[n], acc[m][n]);
  }
  float bv[4];
#pragma unroll
  for (int n = 0; n < 4; ++n) bv[n] = bias[n0 + wc + n * 16 + frow];
#pragma unroll
  for (int m = 0; m < 4; ++m) {
#pragma unroll
    for (int n = 0; n < 4; ++n) {
#pragma unroll
      for (int r = 0; r < 4; ++r) {
        const int row = m0 + wr + m * 16 + fch * 4 + r;
        const int col = n0 + wc + n * 16 + frow;
        float v = acc[m][n][r] + bv[n];
        if (RELU) v = fmaxf(v, 0.0f);
        outp[(long)row * N + col] = __float2bfloat16(v);
      }
    }
  }
}

// ---------------- fused flash attention ----------------
// 128-row Q tile (8 waves), 64-key K tiles, K/V register-prefetched (T14).
// qkv: [rows][1536] bf16 (q | k | v).  chunked = chunk0 + blockIdx.z.
__global__ __launch_bounds__(512) void attn_kernel(const bf16* __restrict__ qkv,
                                                   bf16* __restrict__ aout, int chunk0) {
  __shared__ char Qs[128 * 128];
  __shared__ char Ks[64 * 128];
  __shared__ char Vs[64 * 128];  // transposed: [dk][key], SWZ layout
  __shared__ char Ps[8][16 * 128];
  const int tid = threadIdx.x, lane = tid & 63, wave = tid >> 6;
  const int qb = blockIdx.x, bh = blockIdx.y;
  const int chunked = chunk0 + (int)blockIdx.z;
  const long tb = (long)blockIdx.z * 8192 + (long)(bh >> 3) * 1024;
  const int hh = bh & 7;
  const int q0 = qb * 128;
  const int sr = tid >> 3, ss = tid & 7;
#pragma unroll
  for (int p = 0; p < 2; ++p) {
    const int rr = sr + p * 64;
    const uint4 d = *(const uint4*)(qkv + (tb + q0 + rr) * 1536 + hh * 64 + ss * 8);
    *(uint4*)(Qs + rr * 128 + ((ss * 16) ^ ((rr & 7) << 4))) = d;
  }
  __syncthreads();
  const int frow = lane & 15, fch = lane >> 4;
  const v8s qa0 = *(const v8s*)SWZ(Qs, wave * 16 + frow, fch * 16);
  const v8s qa1 = *(const v8s*)SWZ(Qs, wave * 16 + frow, 64 + fch * 16);
  v4f accv[4] = {};
  float m_run[4], l_run[4];
#pragma unroll
  for (int r = 0; r < 4; ++r) {
    m_run[r] = -1e30f;
    l_run[r] = 0.0f;
  }
  int kt0 = 0, kt1 = 16;
  if (chunked) {
    kt0 = qb * 2 - 1;
    if (kt0 < 0) kt0 = 0;
    kt1 = qb * 2 + 2;
  }
  // register prefetch of first K/V tile (issues before loop; in flight over Q setup)
  uint4 kreg, vreg;
  {
    const long ro = (tb + kt0 * 64 + sr) * 1536 + hh * 64 + ss * 8;
    kreg = *(const uint4*)(qkv + ro + 512);
    vreg = *(const uint4*)(qkv + ro + 1024);
  }
  for (int kt = kt0; kt < kt1; ++kt) {
    __syncthreads();  // previous compute done reading Ks/Vs
    *(uint4*)(Ks + sr * 128 + ((ss * 16) ^ ((sr & 7) << 4))) = kreg;
    {
      const bf16* ve = (const bf16*)&vreg;
#pragma unroll
      for (int e = 0; e < 8; ++e) {
        const int ee = (e + ss) & 7;  // rotate by ss: banks spread across lanes
        const int dk = ss * 8 + ee;
        *(bf16*)(Vs + dk * 128 + ((sr * 2) ^ ((dk & 7) << 4))) = ve[ee];
      }
    }
    if (kt + 1 < kt1) {  // issue next tile's loads: in flight during compute below
      const long ro = (tb + (kt + 1) * 64 + sr) * 1536 + hh * 64 + ss * 8;
      kreg = *(const uint4*)(qkv + ro + 512);
      vreg = *(const uint4*)(qkv + ro + 1024);
    }
    __syncthreads();
    v4f s4[4];
    __builtin_amdgcn_s_setprio(1);
#pragma unroll
    for (int n = 0; n < 4; ++n) {
      const v8s kb0 = *(const v8s*)SWZ(Ks, n * 16 + frow, fch * 16);
      const v8s kb1 = *(const v8s*)SWZ(Ks, n * 16 + frow, 64 + fch * 16);
      v4f z = {0.f, 0.f, 0.f, 0.f};
      z = mfma16(qa0, kb0, z);
      z = mfma16(qa1, kb1, z);
      s4[n] = z * 0.125f;  // 1/sqrt(64)
    }
    __builtin_amdgcn_s_setprio(0);
    if (chunked) {
#pragma unroll
      for (int n = 0; n < 4; ++n) {
        const int kb_ = (kt * 64 + n * 16 + frow) >> 4;
#pragma unroll
        for (int r = 0; r < 4; ++r) {
          const int qb_ = (q0 + wave * 16 + fch * 4 + r) >> 4;
          if (!(kb_ <= qb_ && qb_ - kb_ <= 4)) s4[n][r] = -1e30f;
        }
      }
    }
    float mnew[4], esc[4];
#pragma unroll
    for (int r = 0; r < 4; ++r) {
      float v = fmaxf(fmaxf(s4[0][r], s4[1][r]), fmaxf(s4[2][r], s4[3][r]));
      v = fmaxf(v, __shfl_xor(v, 1));
      v = fmaxf(v, __shfl_xor(v, 2));
      v = fmaxf(v, __shfl_xor(v, 4));
      v = fmaxf(v, __shfl_xor(v, 8));
      mnew[r] = fmaxf(m_run[r], v);
      esc[r] = __expf(m_run[r] - mnew[r]);
    }
#pragma unroll
    for (int n = 0; n < 4; ++n)
#pragma unroll
      for (int r = 0; r < 4; ++r) s4[n][r] = __expf(s4[n][r] - mnew[r]);
#pragma unroll
    for (int r = 0; r < 4; ++r) {
      float v = s4[0][r] + s4[1][r] + s4[2][r] + s4[3][r];
      v += __shfl_xor(v, 1);
      v += __shfl_xor(v, 2);
      v += __shfl_xor(v, 4);
      v += __shfl_xor(v, 8);
      l_run[r] = l_run[r] * esc[r] + v;
      m_run[r] = mnew[r];
    }
#pragma unroll
    for (int f = 0; f < 4; ++f)
#pragma unroll
      for (int r = 0; r < 4; ++r) accv[f][r] *= esc[r];
    char* Pw = Ps[wave];  // wave-private 16x64 P strip, HROW swizzle
#pragma unroll
    for (int n = 0; n < 4; ++n)
#pragma unroll
      for (int r = 0; r < 4; ++r) {
        const int rl = fch * 4 + r;
        *(bf16*)(Pw + rl * 128 + (((n * 16 + frow) * 2) ^ (HROW(rl) << 4))) =
            __float2bfloat16(s4[n][r]);
      }
    const v8s pa0 = *(const v8s*)(Pw + frow * 128 + ((fch * 16) ^ (HROW(frow) << 4)));
    const v8s pa1 = *(const v8s*)(Pw + frow * 128 + ((64 + fch * 16) ^ (HROW(frow) << 4)));
    __builtin_amdgcn_s_setprio(1);
#pragma unroll
    for (int f = 0; f < 4; ++f) {
      const v8s vb0 = *(const v8s*)SWZ(Vs, f * 16 + frow, fch * 16);
      const v8s vb1 = *(const v8s*)SWZ(Vs, f * 16 + frow, 64 + fch * 16);
      accv[f] = mfma16(pa0, vb0, accv[f]);
      accv[f] = mfma16(pa1, vb1, accv[f]);
    }
    __builtin_amdgcn_s_setprio(0);
  }
#pragma unroll
  for (int f = 0; f < 4; ++f)
#pragma unroll
    for (int r = 0; r < 4; ++r) {
      const long row = tb + q0 + wave * 16 + fch * 4 + r;
      aout[row * 512 + hh * 64 + f * 16 + frow] = __float2bfloat16(accv[f][r] / l_run[r]);
    }
}

struct Bufs {
  bf16 *Wqkv, *Wo, *W1, *W2;
  float* bqkv;
  float* x;
  bf16 *h, *qkv, *attn;
  size_t need;
};

static Bufs make_layout(char* ws, long rows) {
  size_t off = 0;
  auto al = [&](size_t b) -> void* {
    void* p = ws + off;
    off += (b + 255) & ~(size_t)255;
    return p;
  };
  Bufs B;
  B.Wqkv = (bf16*)al((size_t)6 * 1536 * 512 * 2);
  B.Wo = (bf16*)al((size_t)6 * 512 * 512 * 2);
  B.W1 = (bf16*)al((size_t)6 * 2048 * 512 * 2);
  B.W2 = (bf16*)al((size_t)6 * 512 * 2048 * 2);
  B.bqkv = (float*)al((size_t)6 * 1536 * 4);
  B.x = (float*)al((size_t)rows * 512 * 4);
  B.h = (bf16*)al((size_t)rows * 512 * 2);
  B.qkv = (bf16*)al((size_t)rows * 1536 * 2);   // qkv and attn contiguous:
  B.attn = (bf16*)al((size_t)rows * 512 * 2);   // ff[rows][2048] aliases both
  B.need = off;
  return B;
}

extern "C" void kernel_launch(void* const* d_in, const int* in_sizes, int n_in, void* d_out,
                              int out_size, void* d_ws, size_t ws_size, hipStream_t stream) {
  const float* xs = (const float*)d_in[0];
  const int* masks = (const int*)d_in[1];
  const float* emb_w = (const float*)d_in[2];
  const float* emb_b = (const float*)d_in[3];
  const float* emb_g = (const float*)d_in[4];
  const float* emb_beta = (const float*)d_in[5];
  const float* wq = (const float*)d_in[6];
  const float* bq = (const float*)d_in[7];
  const float* wk = (const float*)d_in[8];
  const float* bk = (const float*)d_in[9];
  const float* wv = (const float*)d_in[10];
  const float* bv = (const float*)d_in[11];
  const float* wo = (const float*)d_in[12];
  const float* bo = (const float*)d_in[13];
  const float* ln1g = (const float*)d_in[14];
  const float* ln1b = (const float*)d_in[15];
  const float* ln2g = (const float*)d_in[16];
  const float* ln2b = (const float*)d_in[17];
  const float* f1w = (const float*)d_in[18];
  const float* f1b = (const float*)d_in[19];
  const float* f2w = (const float*)d_in[20];
  const float* f2b = (const float*)d_in[21];
  const float* fing = (const float*)d_in[22];
  const float* finb = (const float*)d_in[23];

  char* ws = (char*)d_ws;
  Bufs bm = make_layout(ws, 16384);
  const bool merged = bm.need <= ws_size;
  Bufs b = merged ? bm : make_layout(ws, 8192);
  const long rows = merged ? 16384 : 8192;
  const int npass = merged ? 1 : 2;
  const int mg = (int)(rows / 128);   // gemm grid.x
  const int zdim = (int)(rows / 8192);

  // weight prep: bf16 + transpose to [N][K]
  trconv_kernel<<<dim3(16, 16, 6), 256, 0, stream>>>(wq, b.Wqkv, 512, 512, (long)512 * 512,
                                                     (long)1536 * 512);
  trconv_kernel<<<dim3(16, 16, 6), 256, 0, stream>>>(wk, b.Wqkv + 512 * 512, 512, 512,
                                                     (long)512 * 512, (long)1536 * 512);
  trconv_kernel<<<dim3(16, 16, 6), 256, 0, stream>>>(wv, b.Wqkv + 1024 * 512, 512, 512,
                                                     (long)512 * 512, (long)1536 * 512);
  trconv_kernel<<<dim3(16, 16, 6), 256, 0, stream>>>(wo, b.Wo, 512, 512, (long)512 * 512,
                                                     (long)512 * 512);
  trconv_kernel<<<dim3(64, 16, 6), 256, 0, stream>>>(f1w, b.W1, 512, 2048, (long)512 * 2048,
                                                     (long)2048 * 512);
  trconv_kernel<<<dim3(16, 64, 6), 256, 0, stream>>>(f2w, b.W2, 2048, 512, (long)2048 * 512,
                                                     (long)512 * 2048);
  biascat_kernel<<<36, 256, 0, stream>>>(bq, bk, bv, b.bqkv);

  for (int pass = 0; pass < npass; ++pass) {
    embed_kernel<<<(int)rows, 256, 0, stream>>>(xs, emb_w, emb_b, emb_g, emb_beta, b.x);
    ln_kernel<<<(int)rows, 256, 0, stream>>>(b.x, ln1g, ln1b, b.h);
    for (int l = 0; l < 6; ++l) {
      gemm_kernel<false><<<dim3(mg, 12), 256, 0, stream>>>(
          b.h, b.Wqkv + (size_t)l * 1536 * 512, b.bqkv + l * 1536, b.qkv, (int)rows, 1536, 512);
      attn_kernel<<<dim3(8, 64, zdim), 512, 0, stream>>>(b.qkv, b.attn, merged ? 0 : pass);
      gemm_kernel<false><<<dim3(mg, 4), 256, 0, stream>>>(
          b.attn, b.Wo + (size_t)l * 512 * 512, bo + l * 512, b.h, (int)rows, 512, 512);
      add_ln_kernel<0><<<(int)rows, 256, 0, stream>>>(b.x, b.h, ln2g + l * 512, ln2b + l * 512,
                                                      b.h);
      gemm_kernel<true><<<dim3(mg, 16), 256, 0, stream>>>(
          b.h, b.W1 + (size_t)l * 2048 * 512, f1b + l * 2048, b.qkv /*ff*/, (int)rows, 2048, 512);
      gemm_kernel<false><<<dim3(mg, 4), 256, 0, stream>>>(
          b.qkv /*ff*/, b.W2 + (size_t)l * 512 * 2048, f2b + l * 512, b.h, (int)rows, 512, 2048);
      if (l < 5)
        add_ln_kernel<0><<<(int)rows, 256, 0, stream>>>(b.x, b.h, ln1g + (l + 1) * 512,
                                                        ln1b + (l + 1) * 512, b.h);
      else
        add_ln_kernel<1><<<(int)rows, 256, 0, stream>>>(
            b.x, b.h, fing, finb, (float*)d_out + (size_t)pass * 8192 * 512);
    }
  }
  maskout_kernel<<<32, 256, 0, stream>>>(masks, (float*)d_out + (size_t)2 * 8192 * 512, 8192);
  (void)in_sizes;
  (void)n_in;
  (void)out_size;
}